// Round 6
// baseline (248.324 us; speedup 1.0000x reference)
//
#include <hip/hip_runtime.h>
#include <hip/hip_fp16.h>

#define G 128

typedef _Float16 h2_t __attribute__((ext_vector_type(2)));

union U16 { uint4 u; h2_t h2[4]; };
union HV  { uint4 u; h2_t h2[4]; };
union PK2 { uint2 u; h2_t h[2]; };

__device__ __forceinline__ float dot2f(h2_t a, h2_t b, float c) {
#if __has_builtin(__builtin_amdgcn_fdot2)
    return __builtin_amdgcn_fdot2(a, b, c, false);
#else
    return c + (float)a.x * (float)b.x + (float)a.y * (float)b.y;
#endif
}

__device__ __forceinline__ h2_t h2max(h2_t a, h2_t b) {
#if __has_builtin(__builtin_elementwise_max)
    return __builtin_elementwise_max(a, b);
#else
    h2_t r;
    r.x = a.x > b.x ? a.x : b.x;
    r.y = a.y > b.y ? a.y : b.y;
    return r;
#endif
}

__device__ __forceinline__ float dot4(float4 a, float4 b) {
    return a.x * b.x + a.y * b.y + a.z * b.z + a.w * b.w;
}

// ---------------------------------------------------------------------------
// FUSED KERNEL: conv1+relu+m0+pool -> conv2+relu+m1+pool -> tconv1+relu+m3 ->
// tconv2+sigmoid+m4, one dispatch, no intermediate HBM traffic.
//
// Rationale (round 5 post-mortem): conv1 and conv2 each sat at ~40-43us, just
// under the 43.5us workspace-fill in the top-5 — combined ~85us vs ~20us of
// roofline floors, dominated by the h1p/m1 round-trip (~55MB), dispatch
// drains, and phase serialization. Fusing removes all three.
//
// Per block (grid 8x8x64 = 4096 = 2 batches x 32 z-slabs x 8y x 8x):
//   out region: level-0 z[4*bz2,+4) y[16*by,+16) x[16*bx,+16)   (4KB f32)
//   needs: level-2 parents 4x4x1 -> level-1 conv2 outs 8x8x2
//        -> level-1 tile WITH conv2 halo: 10x10x4 (overlap-recomputed)
//        -> level-0 staged halo: 24(x) x 22(y) x 10(z) (x*m0 fp16 + occ bits)
// Phases (3 barriers):
//   0. reg-stage 1320 x (occ int4 + x float4); LDS init (weights, counters)
//   1. write sx/mask; barrier
//   2. conv1+pool per level-1 tile voxel (400): 48 ds_read_b32 -> 4x4x6 h2
//      register cube (statically indexed), 8 mask-guarded children x 27-tap
//      fp16 pk_fma, h2max pool -> tile + sm1L. barrier
//   3. conv2: ballot-compacted actives (<=128, ~57%) read tile from LDS,
//      864 dot2 each; atomicMax-pool (relu'd f32 bits, monotonic) -> pacc;
//      barrier
//   4. decoder: 256 thr = 16 parents x (a,bb,e,f); 1 float4 store each.
// Math is bit-identical to the round-4/5 verified pipeline.
// No min-waves launch-bounds (round-2 spill lesson). LDS ~32.4KB -> 4 blk/CU.
// ---------------------------------------------------------------------------
__global__ __launch_bounds__(256)
void k_fused(const float* __restrict__ x, const int* __restrict__ occ,
             const float* __restrict__ W1, const float* __restrict__ W2,
             const float* __restrict__ Wt1, const float* __restrict__ Wt2,
             float* __restrict__ out)
{
    __shared__ __align__(16) _Float16      sx[10 * 22 * 24];   // 10560 B
    __shared__ __align__(4)  unsigned char mk[10 * 22 * 6];    // 1320 B
    __shared__ __align__(16) uint4         tile[2 * 400];      // 12800 B
    __shared__ unsigned char               sm1L[400];          // 400 B
    __shared__ __align__(16) h2_t          w1L[216];           // 864 B
    __shared__ __align__(16) h2_t          w2L[864];           // 3456 B
    __shared__ float4                      wt1[128];           // 2048 B
    __shared__ float4                      wt2[32];            // 512 B
    __shared__ int                         pacc[64];           // [co][parent]
    __shared__ int                         pm[16];
    __shared__ unsigned char               clist[128];
    __shared__ int                         scnt;

    const int tid = threadIdx.x;

    // ---- bijective XCD swizzle: 4096 = 8 XCD x 512 contiguous ----
    const int lin = blockIdx.x + 8 * (blockIdx.y + 8 * blockIdx.z);
    const int wrk = ((lin & 7) << 9) | (lin >> 3);
    const int bx  = wrk & 7, by = (wrk >> 3) & 7;
    const int bzz = wrk >> 6;                 // 0..63
    const int b   = bzz >> 5, bz2 = bzz & 31; // batch, level-2 z (level-1 z0 = 2*bz2)

    const int base_b = b * G * G * G;
    const int gz0 = 4 * bz2 - 3;              // stage z origin (10 layers)
    const int gy0 = 16 * by - 3;              // stage y origin (22 rows)
    const int gx0 = 16 * bx - 4;              // stage x origin (24 = 6 chunks)

    // ---- phase 0a: issue ALL staging loads (1320 chunks, 6/thread) ----
    int4   ro[6];
    float4 rx[6];
    #pragma unroll
    for (int it = 0; it < 6; ++it) {
        int c = it * 256 + tid;
        int cc = c < 1320 ? c : 1319;          // clamp: harmless duplicate
        int row = cc / 6, seg = cc - row * 6;  // row in [0,220)
        int lz = row / 22, ly = row - lz * 22;
        int gz = gz0 + lz, gy = gy0 + ly, gxc = gx0 + (seg << 2);
        bool inb = (unsigned)gz < 128u && (unsigned)gy < 128u && (unsigned)gxc < 128u;
        int gi = inb ? base_b + (gz * G + gy) * G + gxc : base_b;
        ro[it] = *(const int4*)(occ + gi);
        rx[it] = *(const float4*)(x + gi);
    }

    // ---- phase 0b: LDS init (independent of loads above) ----
    if (tid == 0) scnt = 0;
    if (tid < 64) pacc[tid] = 0;
    if (tid < 16) pm[tid] = 0;
    if (tid < 128) wt1[tid] = ((const float4*)Wt1)[tid];
    if (tid < 32)  wt2[tid] = ((const float4*)Wt2)[tid];
    if (tid < 216) {
        float2 f = ((const float2*)W1)[tid];
        h2_t w; w.x = (_Float16)f.x; w.y = (_Float16)f.y;
        w1L[tid] = w;
    }
    #pragma unroll
    for (int it = 0; it < 4; ++it) {
        int i = it * 256 + tid;
        if (i < 864) {
            int t = i >> 5, rr = i & 31, co = rr >> 3, p = rr & 7;
            h2_t w;
            w.x = (_Float16)W2[t * 64 + (2 * p) * 4 + co];
            w.y = (_Float16)W2[t * 64 + (2 * p + 1) * 4 + co];
            w2L[i] = w;
        }
    }

    // ---- phase 1: write sx (masked fp16) + occupancy nibbles ----
    #pragma unroll
    for (int it = 0; it < 6; ++it) {
        int c = it * 256 + tid;
        if (c < 1320) {
            int row = c / 6, seg = c - row * 6;
            int lz = row / 22, ly = row - lz * 22;
            int gz = gz0 + lz, gy = gy0 + ly, gxc = gx0 + (seg << 2);
            bool inb = (unsigned)gz < 128u && (unsigned)gy < 128u && (unsigned)gxc < 128u;
            int4   o4 = ro[it];
            float4 x4 = rx[it];
            if (!inb) o4 = make_int4(1, 1, 1, 1);
            h2_t p01, p23;
            p01.x = (o4.x == 0) ? (_Float16)x4.x : (_Float16)0.f;
            p01.y = (o4.y == 0) ? (_Float16)x4.y : (_Float16)0.f;
            p23.x = (o4.z == 0) ? (_Float16)x4.z : (_Float16)0.f;
            p23.y = (o4.w == 0) ? (_Float16)x4.w : (_Float16)0.f;
            PK2 pk; pk.h[0] = p01; pk.h[1] = p23;
            *(uint2*)&sx[row * 24 + (seg << 2)] = pk.u;
            mk[c] = (unsigned char)((o4.x == 0 ? 1 : 0) | (o4.y == 0 ? 2 : 0) |
                                    (o4.z == 0 ? 4 : 0) | (o4.w == 0 ? 8 : 0));
        }
    }
    __syncthreads();

    // ---- phase 2: conv1 + relu + pool -> level-1 tile [4][10][10] ----
    {
        const h2_t zero = (h2_t)(_Float16)0.f;
        const h2_t* sxh2 = (const h2_t*)sx;
        #pragma unroll
        for (int pass = 0; pass < 2; ++pass) {
            int t = pass * 256 + tid;
            if (t < 400) {
                const int tz = t / 100, rm = t - tz * 100;
                const int ty = rm / 10,  tx = rm - ty * 10;

                // 4x4x6-value register cube (48 aligned ds_read_b32)
                h2_t cube[4][4][3];
                #pragma unroll
                for (int z4 = 0; z4 < 4; ++z4) {
                    const int lz = 2 * tz + z4;
                    #pragma unroll
                    for (int y4 = 0; y4 < 4; ++y4) {
                        const int base = (lz * 22 + 2 * ty + y4) * 12 + tx;
                        cube[z4][y4][0] = sxh2[base];
                        cube[z4][y4][1] = sxh2[base + 1];
                        cube[z4][y4][2] = sxh2[base + 2];
                    }
                }

                h2_t best[8];
                #pragma unroll
                for (int c = 0; c < 8; ++c) best[c] = zero;
                int anym = 0;

                #pragma unroll
                for (int pos = 0; pos < 8; ++pos) {
                    const int dz = pos >> 2, dy = (pos >> 1) & 1, dx = pos & 1;
                    const int lz = 1 + 2 * tz + dz;
                    const int ly = 1 + 2 * ty + dy;
                    const int lx = 2 + 2 * tx + dx;
                    const int mbit = (mk[(lz * 22 + ly) * 6 + (lx >> 2)] >> (lx & 3)) & 1;
                    if (mbit) {
                        anym = 1;
                        h2_t acc[8];
                        #pragma unroll
                        for (int c = 0; c < 8; ++c) acc[c] = zero;
                        #pragma unroll
                        for (int kz = 0; kz < 3; ++kz)
                        #pragma unroll
                        for (int ky = 0; ky < 3; ++ky)
                        #pragma unroll
                        for (int kx = 0; kx < 3; ++kx) {
                            const int xp = dx + kx + 1;
                            h2_t cv = cube[dz + kz][dy + ky][xp >> 1];
                            _Float16 v = (xp & 1) ? cv.y : cv.x;
                            h2_t v2 = {v, v};
                            const h2_t* w = &w1L[((kz * 3 + ky) * 3 + kx) * 8];
                            #pragma unroll
                            for (int c = 0; c < 8; ++c) acc[c] = v2 * w[c] + acc[c];
                        }
                        #pragma unroll
                        for (int c = 0; c < 8; ++c)
                            best[c] = h2max(best[c], h2max(acc[c], zero));
                    }
                }

                HV p0, p1;
                #pragma unroll
                for (int c = 0; c < 4; ++c) { p0.h2[c] = best[c]; p1.h2[c] = best[4 + c]; }
                tile[t]       = p0.u;
                tile[400 + t] = p1.u;
                sm1L[t] = (unsigned char)anym;
            }
        }
    }
    __syncthreads();

    // ---- phase 3: conv2 on <=128 outputs (ballot compaction) ----
    {
        const int ox = tid & 7, oy = (tid >> 3) & 7, oz = tid >> 6;  // oz<2 iff tid<128
        bool act = false;
        if (tid < 128)
            act = sm1L[((oz + 1) * 10 + oy + 1) * 10 + ox + 1] != 0;
        const int lane = tid & 63;
        unsigned long long bal = __ballot(act);
        int wtot = __popcll(bal);
        int wbase = 0;
        if (lane == 0 && wtot) wbase = atomicAdd(&scnt, wtot);
        wbase = __shfl(wbase, 0);
        if (act) {
            int pre = __popcll(bal & ((1ull << lane) - 1ull));
            clist[wbase + pre] = (unsigned char)tid;
            pm[(oy >> 1) * 4 + (ox >> 1)] = 1;   // benign race: all write 1
        }
    }
    __syncthreads();

    const int n = scnt;   // <=128, ~73 at 57% density

    if (tid < n) {
        const int code = clist[tid];
        const int ox = code & 7, oy = (code >> 3) & 7, oz = code >> 6;
        float acc[4] = {0.f, 0.f, 0.f, 0.f};
        #pragma unroll
        for (int kz = 0; kz < 3; ++kz)
        #pragma unroll
        for (int ky = 0; ky < 3; ++ky) {
            const int rb = ((oz + kz) * 10 + (oy + ky)) * 10 + ox;
            h2_t hp[2][3][4];
            #pragma unroll
            for (int hh = 0; hh < 2; ++hh)
            #pragma unroll
            for (int xi = 0; xi < 3; ++xi) {
                U16 a; a.u = tile[hh * 400 + rb + xi];
                #pragma unroll
                for (int p = 0; p < 4; ++p) hp[hh][xi][p] = a.h2[p];
            }
            const int t3 = (kz * 3 + ky) * 3;
            #pragma unroll
            for (int kx = 0; kx < 3; ++kx) {
                const h2_t* w = &w2L[(t3 + kx) * 32];   // uniform -> broadcast
                #pragma unroll
                for (int co = 0; co < 4; ++co) {
                    float a = acc[co];
                    #pragma unroll
                    for (int hh = 0; hh < 2; ++hh)
                    #pragma unroll
                    for (int p = 0; p < 4; ++p)
                        a = dot2f(hp[hh][kx][p], w[co * 8 + 4 * hh + p], a);
                    acc[co] = a;
                }
            }
        }
        // active => m1 == 1 exactly; pool via monotonic f32-bit atomicMax
        const int parent = (oy >> 1) * 4 + (ox >> 1);
        #pragma unroll
        for (int co = 0; co < 4; ++co)
            atomicMax(&pacc[co * 16 + parent],
                      __float_as_int(fmaxf(acc[co], 0.f)));
    }
    __syncthreads();

    // ---- phase 4: decoder, thread = (parent p, a, bb, e, f) ----
    {
        const int p  = tid >> 4;
        const int a  = (tid >> 3) & 1;
        const int bb = (tid >> 2) & 1;
        const int e  = (tid >> 1) & 1;
        const int f  = tid & 1;
        const int pY = p >> 2, pq = p & 3;
        const int py = by * 4 + pY, pxq = bx * 4 + pq;

        const float mm = pm[p] ? 1.f : 0.f;
        const float4 hv = make_float4(__int_as_float(pacc[p]),
                                      __int_as_float(pacc[16 + p]),
                                      __int_as_float(pacc[32 + p]),
                                      __int_as_float(pacc[48 + p]));

        const int b0q = ((((1 - a) * 2 + (1 - bb)) * 2) + 1) * 16;  // c=0 -> kc=1
        const int b1q = ((((1 - a) * 2 + (1 - bb)) * 2) + 0) * 16;  // c=1 -> kc=0
        float4 t0q[4], t1q[4];
        #pragma unroll
        for (int q = 0; q < 4; ++q) {
            float4 a0 = wt1[b0q + q],      a1 = wt1[b0q + 4 + q];
            float4 a2 = wt1[b0q + 8 + q],  a3 = wt1[b0q + 12 + q];
            float4 c0 = wt1[b1q + q],      c1 = wt1[b1q + 4 + q];
            float4 c2 = wt1[b1q + 8 + q],  c3 = wt1[b1q + 12 + q];
            float4 s0, s1;
            s0.x = hv.x * a0.x + hv.y * a1.x + hv.z * a2.x + hv.w * a3.x;
            s0.y = hv.x * a0.y + hv.y * a1.y + hv.z * a2.y + hv.w * a3.y;
            s0.z = hv.x * a0.z + hv.y * a1.z + hv.z * a2.z + hv.w * a3.z;
            s0.w = hv.x * a0.w + hv.y * a1.w + hv.z * a2.w + hv.w * a3.w;
            s1.x = hv.x * c0.x + hv.y * c1.x + hv.z * c2.x + hv.w * c3.x;
            s1.y = hv.x * c0.y + hv.y * c1.y + hv.z * c2.y + hv.w * c3.y;
            s1.z = hv.x * c0.z + hv.y * c1.z + hv.z * c2.z + hv.w * c3.z;
            s1.w = hv.x * c0.w + hv.y * c1.w + hv.z * c2.w + hv.w * c3.w;
            t0q[q] = make_float4(fmaxf(s0.x, 0.f), fmaxf(s0.y, 0.f),
                                 fmaxf(s0.z, 0.f), fmaxf(s0.w, 0.f));
            t1q[q] = make_float4(fmaxf(s1.x, 0.f), fmaxf(s1.y, 0.f),
                                 fmaxf(s1.z, 0.f), fmaxf(s1.w, 0.f));
        }

        const int d  = 4 * bz2 + 2 * a + e;
        const int hh = 4 * py + 2 * bb + f;
        const int be = ((1 - e) * 2 + (1 - f)) * 2;
        const float4* wg0 = &wt2[(be + 1) * 4];   // g=0 -> kg=1
        const float4* wg1 = &wt2[(be + 0) * 4];   // g=1 -> kg=0
        float s00 = dot4(t0q[0], wg0[0]) + dot4(t0q[1], wg0[1])
                  + dot4(t0q[2], wg0[2]) + dot4(t0q[3], wg0[3]);
        float s01 = dot4(t0q[0], wg1[0]) + dot4(t0q[1], wg1[1])
                  + dot4(t0q[2], wg1[2]) + dot4(t0q[3], wg1[3]);
        float s10 = dot4(t1q[0], wg0[0]) + dot4(t1q[1], wg0[1])
                  + dot4(t1q[2], wg0[2]) + dot4(t1q[3], wg0[3]);
        float s11 = dot4(t1q[0], wg1[0]) + dot4(t1q[1], wg1[1])
                  + dot4(t1q[2], wg1[2]) + dot4(t1q[3], wg1[3]);
        float4 o;
        o.x = mm / (1.f + __expf(-s00));
        o.y = mm / (1.f + __expf(-s01));
        o.z = mm / (1.f + __expf(-s10));
        o.w = mm / (1.f + __expf(-s11));
        *(float4*)&out[((b * G + d) * G + hh) * G + 4 * pxq] = o;
    }
}

extern "C" void kernel_launch(void* const* d_in, const int* in_sizes, int n_in,
                              void* d_out, int out_size, void* d_ws, size_t ws_size,
                              hipStream_t stream) {
    (void)in_sizes; (void)n_in; (void)out_size; (void)d_ws; (void)ws_size;
    const float* x   = (const float*)d_in[0];
    const float* W1  = (const float*)d_in[1];
    const float* W2  = (const float*)d_in[2];
    const float* Wt1 = (const float*)d_in[3];
    const float* Wt2 = (const float*)d_in[4];
    const int*   occ = (const int*)d_in[5];
    float* out = (float*)d_out;

    k_fused<<<dim3(8, 8, 64), dim3(256), 0, stream>>>(x, occ, W1, W2, Wt1, Wt2, out);
}

// Round 7
// 223.235 us; speedup vs baseline: 1.1124x; 1.1124x over previous
//
#include <hip/hip_runtime.h>
#include <hip/hip_fp16.h>

#define G 128

typedef _Float16 h2_t __attribute__((ext_vector_type(2)));

union U16 { uint4 u; h2_t h2[4]; };
union HV  { uint4 u; h2_t h2[4]; };
union PK2 { uint2 u; h2_t h[2]; };

__device__ __forceinline__ float dot2f(h2_t a, h2_t b, float c) {
#if __has_builtin(__builtin_amdgcn_fdot2)
    return __builtin_amdgcn_fdot2(a, b, c, false);
#else
    return c + (float)a.x * (float)b.x + (float)a.y * (float)b.y;
#endif
}

__device__ __forceinline__ float dot4(float4 a, float4 b) {
    return a.x * b.x + a.y * b.y + a.z * b.z + a.w * b.w;
}

// ---------------------------------------------------------------------------
// FUSED KERNEL v2: conv1+relu+m0+pool -> conv2+relu+m1+pool -> decoder.
//
// Round-6 post-mortem: fusion removed the h1p/m1 HBM round-trip (FETCH 19MB,
// WRITE 16MB — as designed) but phase 2 was 182us: (a) per-child `if(mbit)`
// is lane-divergent => dense 8x27x8 fma per wave (round-0 mistake), (b) the
// 48-reg cube at VGPR_Count=44 forced AGPR shuffling (VALUBusy 67%).
//
// v2 phase 2 = the compaction structure proven in rounds 1-3:
//  * active-CHILD list (~320 of 3200, 10% density) built during the staging
//    write loop from occ bits already in registers (ballot-free: per-chunk
//    popc + atomicAdd, round-3 pattern);
//  * compute pass: one active child per thread, 27 scalar LDS taps x 216
//    pk_fma, pool via f32-bit atomicMax into pacc[16][400] (monotonic, relu>=0);
//  * repack pacc -> fp16 tile[2][400] (lossless f32->f16: values are exact
//    fp16), aliased over the DEAD sx+childlist region -> LDS ~50KB, 3 blk/CU.
// conv2 + pool + decoder are byte-identical math to round 6 (verified).
// __launch_bounds__(256,1): round-2/6 lesson — reg staging needs VGPR room.
// Phases/barriers: init | B | stage+list | B | conv1 | B | repack+clist | B |
// conv2+pool | B | decoder.
// ---------------------------------------------------------------------------
__global__ __launch_bounds__(256, 1)
void k_fused(const float* __restrict__ x, const int* __restrict__ occ,
             const float* __restrict__ W1, const float* __restrict__ W2,
             const float* __restrict__ Wt1, const float* __restrict__ Wt2,
             float* __restrict__ out)
{
    // region A: sx (10560B) + childL (6400B) during encode; tile (12800B) after
    __shared__ __align__(16) char          regA[16960];
    __shared__ __align__(16) int           pacc[16 * 400];   // 25600 B
    __shared__ __align__(16) h2_t          w1L[216];         // 864 B
    __shared__ __align__(16) h2_t          w2L[864];         // 3456 B
    __shared__ float4                      wt1[128];         // 2048 B
    __shared__ float4                      wt2[32];          // 512 B
    __shared__ unsigned char               sm1L[400];
    __shared__ unsigned char               clist[128];
    __shared__ int                         pacc2[64];        // [co][parent]
    __shared__ int                         pm[16];
    __shared__ int                         scnt, scnt2;

    _Float16*       sxp    = (_Float16*)regA;
    unsigned short* childL = (unsigned short*)(regA + 10560);
    uint4*          tile   = (uint4*)regA;

    const int tid = threadIdx.x;

    // ---- bijective XCD swizzle: 4096 = 8 XCD x 512 contiguous ----
    const int lin = blockIdx.x + 8 * (blockIdx.y + 8 * blockIdx.z);
    const int wrk = ((lin & 7) << 9) | (lin >> 3);
    const int bx  = wrk & 7, by = (wrk >> 3) & 7;
    const int bzz = wrk >> 6;                 // 0..63
    const int b   = bzz >> 5, bz2 = bzz & 31;

    const int base_b = b * G * G * G;
    const int gz0 = 4 * bz2 - 3;              // 10 staged z layers
    const int gy0 = 16 * by - 3;              // 22 staged y rows
    const int gx0 = 16 * bx - 4;              // 24 staged x = 6 chunks

    // ---- phase 0a: issue ALL staging loads (1320 chunks, 6/thread) ----
    int4   ro[6];
    float4 rx[6];
    #pragma unroll
    for (int it = 0; it < 6; ++it) {
        int c = it * 256 + tid;
        int cc = c < 1320 ? c : 1319;          // clamp: harmless duplicate
        int row = cc / 6, seg = cc - row * 6;  // row in [0,220)
        int lz = row / 22, ly = row - lz * 22;
        int gz = gz0 + lz, gy = gy0 + ly, gxc = gx0 + (seg << 2);
        bool inb = (unsigned)gz < 128u && (unsigned)gy < 128u && (unsigned)gxc < 128u;
        int gi = inb ? base_b + (gz * G + gy) * G + gxc : base_b;
        ro[it] = *(const int4*)(occ + gi);
        rx[it] = *(const float4*)(x + gi);
    }

    // ---- phase 0b: LDS init (independent of loads above) ----
    if (tid == 0) { scnt = 0; scnt2 = 0; }
    #pragma unroll
    for (int it = 0; it < 7; ++it) {            // zero pacc: 1600 uint4
        int i = it * 256 + tid;
        if (i < 1600) ((uint4*)pacc)[i] = make_uint4(0u, 0u, 0u, 0u);
    }
    if (tid < 100) ((unsigned*)sm1L)[tid] = 0u;
    if (tid < 64) pacc2[tid] = 0;
    if (tid < 16) pm[tid] = 0;
    if (tid < 128) wt1[tid] = ((const float4*)Wt1)[tid];
    if (tid < 32)  wt2[tid] = ((const float4*)Wt2)[tid];
    if (tid < 216) {
        float2 f = ((const float2*)W1)[tid];
        h2_t w; w.x = (_Float16)f.x; w.y = (_Float16)f.y;
        w1L[tid] = w;
    }
    #pragma unroll
    for (int it = 0; it < 4; ++it) {
        int i = it * 256 + tid;
        if (i < 864) {
            int t = i >> 5, rr = i & 31, co = rr >> 3, p = rr & 7;
            h2_t w;
            w.x = (_Float16)W2[t * 64 + (2 * p) * 4 + co];
            w.y = (_Float16)W2[t * 64 + (2 * p + 1) * 4 + co];
            w2L[i] = w;
        }
    }
    __syncthreads();   // zeros/counters visible before list atomics

    // ---- phase 1: write sx (masked fp16) + ACTIVE-CHILD list + sm1L ----
    #pragma unroll
    for (int it = 0; it < 6; ++it) {
        int c = it * 256 + tid;
        if (c < 1320) {
            int row = c / 6, seg = c - row * 6;
            int lz = row / 22, ly = row - lz * 22;
            int gz = gz0 + lz, gy = gy0 + ly, gxc = gx0 + (seg << 2);
            bool inb = (unsigned)gz < 128u && (unsigned)gy < 128u && (unsigned)gxc < 128u;
            int4   o4 = ro[it];
            float4 x4 = rx[it];
            if (!inb) o4 = make_int4(1, 1, 1, 1);
            h2_t p01, p23;
            p01.x = (o4.x == 0) ? (_Float16)x4.x : (_Float16)0.f;
            p01.y = (o4.y == 0) ? (_Float16)x4.y : (_Float16)0.f;
            p23.x = (o4.z == 0) ? (_Float16)x4.z : (_Float16)0.f;
            p23.y = (o4.w == 0) ? (_Float16)x4.w : (_Float16)0.f;
            PK2 pk; pk.h[0] = p01; pk.h[1] = p23;
            *(uint2*)&sxp[row * 24 + (seg << 2)] = pk.u;

            // children: lz in [1,8], ly in [1,20], lx in [2,21]
            if ((unsigned)(lz - 1) < 8u && (unsigned)(ly - 1) < 20u) {
                const int lx0 = seg << 2;
                int mb = 0;
                if (o4.x == 0 && (unsigned)(lx0 + 0 - 2) < 20u) mb |= 1;
                if (o4.y == 0 && (unsigned)(lx0 + 1 - 2) < 20u) mb |= 2;
                if (o4.z == 0 && (unsigned)(lx0 + 2 - 2) < 20u) mb |= 4;
                if (o4.w == 0 && (unsigned)(lx0 + 3 - 2) < 20u) mb |= 8;
                if (mb) {
                    int cnt  = __popc(mb);
                    int base = atomicAdd(&scnt, cnt);
                    const int tb = ((lz - 1) >> 1) * 100 + ((ly - 1) >> 1) * 10;
                    #pragma unroll
                    for (int j = 0; j < 4; ++j) {
                        if (mb & (1 << j)) {
                            const int lxv = lx0 + j;
                            childL[base++] = (unsigned short)((lz << 10) | (ly << 5) | lxv);
                            sm1L[tb + ((lxv - 2) >> 1)] = (unsigned char)1;  // benign race
                        }
                    }
                }
            }
        }
    }
    __syncthreads();

    const int n1 = scnt;   // ~320 of 3200 at 10% density

    // ---- phase 2: conv1 on ACTIVE children only; pool via atomicMax ----
    {
        const h2_t zero = (h2_t)(_Float16)0.f;
        for (int kb = 0; kb < n1; kb += 256) {
            const int idx = kb + tid;
            if (idx < n1) {
                const int e  = childL[idx];
                const int lx = e & 31, ly = (e >> 5) & 31, lz = e >> 10;
                const int sb = (lz * 22 + ly) * 24 + lx;
                h2_t acc[8];
                #pragma unroll
                for (int c = 0; c < 8; ++c) acc[c] = zero;
                #pragma unroll
                for (int kz = 0; kz < 3; ++kz)
                #pragma unroll
                for (int ky = 0; ky < 3; ++ky)
                #pragma unroll
                for (int kx = 0; kx < 3; ++kx) {
                    _Float16 v = sxp[sb + (kz - 1) * 528 + (ky - 1) * 24 + (kx - 1)];
                    h2_t v2 = {v, v};
                    const h2_t* w = &w1L[((kz * 3 + ky) * 3 + kx) * 8];  // uniform
                    #pragma unroll
                    for (int c = 0; c < 8; ++c) acc[c] = v2 * w[c] + acc[c];
                }
                const int t = ((lz - 1) >> 1) * 100 + ((ly - 1) >> 1) * 10 + ((lx - 2) >> 1);
                #pragma unroll
                for (int c = 0; c < 8; ++c) {
                    atomicMax(&pacc[(2 * c) * 400 + t],
                              __float_as_int(fmaxf((float)acc[c].x, 0.f)));
                    atomicMax(&pacc[(2 * c + 1) * 400 + t],
                              __float_as_int(fmaxf((float)acc[c].y, 0.f)));
                }
            }
        }
    }
    __syncthreads();   // pacc final; sx/childL now DEAD

    // ---- phase 3a: repack pacc -> fp16 tile (over dead region A) ----
    #pragma unroll
    for (int pass = 0; pass < 2; ++pass) {
        int t = pass * 256 + tid;
        if (t < 400) {
            HV p0, p1;
            #pragma unroll
            for (int c = 0; c < 4; ++c) {
                h2_t a, bq;
                a.x  = (_Float16)__int_as_float(pacc[(2 * c) * 400 + t]);
                a.y  = (_Float16)__int_as_float(pacc[(2 * c + 1) * 400 + t]);
                bq.x = (_Float16)__int_as_float(pacc[(8 + 2 * c) * 400 + t]);
                bq.y = (_Float16)__int_as_float(pacc[(9 + 2 * c) * 400 + t]);
                p0.h2[c] = a; p1.h2[c] = bq;
            }
            tile[t]       = p0.u;
            tile[400 + t] = p1.u;
        }
    }
    // ---- phase 3b: conv2 active list (sm1L final since last barrier) ----
    {
        const int ox = tid & 7, oy = (tid >> 3) & 7, oz = tid >> 6;
        bool act = false;
        if (tid < 128)
            act = sm1L[(oz + 1) * 100 + (oy + 1) * 10 + ox + 1] != 0;
        const int lane = tid & 63;
        unsigned long long bal = __ballot(act);
        int wtot = __popcll(bal);
        int wbase = 0;
        if (lane == 0 && wtot) wbase = atomicAdd(&scnt2, wtot);
        wbase = __shfl(wbase, 0);
        if (act) {
            int pre = __popcll(bal & ((1ull << lane) - 1ull));
            clist[wbase + pre] = (unsigned char)tid;
            pm[(oy >> 1) * 4 + (ox >> 1)] = 1;   // benign race
        }
    }
    __syncthreads();

    const int n2 = scnt2;   // <=128, ~73 at 57% density

    // ---- phase 4: conv2 + relu + pool (atomicMax, monotonic) ----
    if (tid < n2) {
        const int code = clist[tid];
        const int ox = code & 7, oy = (code >> 3) & 7, oz = code >> 6;
        float acc[4] = {0.f, 0.f, 0.f, 0.f};
        #pragma unroll
        for (int kz = 0; kz < 3; ++kz)
        #pragma unroll
        for (int ky = 0; ky < 3; ++ky) {
            const int rb = ((oz + kz) * 10 + (oy + ky)) * 10 + ox;
            h2_t hp[2][3][4];
            #pragma unroll
            for (int hh = 0; hh < 2; ++hh)
            #pragma unroll
            for (int xi = 0; xi < 3; ++xi) {
                U16 a; a.u = tile[hh * 400 + rb + xi];
                #pragma unroll
                for (int p = 0; p < 4; ++p) hp[hh][xi][p] = a.h2[p];
            }
            const int t3 = (kz * 3 + ky) * 3;
            #pragma unroll
            for (int kx = 0; kx < 3; ++kx) {
                const h2_t* w = &w2L[(t3 + kx) * 32];   // uniform -> broadcast
                #pragma unroll
                for (int co = 0; co < 4; ++co) {
                    float a = acc[co];
                    #pragma unroll
                    for (int hh = 0; hh < 2; ++hh)
                    #pragma unroll
                    for (int p = 0; p < 4; ++p)
                        a = dot2f(hp[hh][kx][p], w[co * 8 + 4 * hh + p], a);
                    acc[co] = a;
                }
            }
        }
        const int parent = (oy >> 1) * 4 + (ox >> 1);
        #pragma unroll
        for (int co = 0; co < 4; ++co)
            atomicMax(&pacc2[co * 16 + parent],
                      __float_as_int(fmaxf(acc[co], 0.f)));
    }
    __syncthreads();

    // ---- phase 5: decoder, thread = (parent p, a, bb, e, f) ----
    {
        const int p  = tid >> 4;
        const int a  = (tid >> 3) & 1;
        const int bb = (tid >> 2) & 1;
        const int e  = (tid >> 1) & 1;
        const int f  = tid & 1;
        const int pY = p >> 2, pq = p & 3;
        const int py = by * 4 + pY, pxq = bx * 4 + pq;

        const float mm = pm[p] ? 1.f : 0.f;
        const float4 hv = make_float4(__int_as_float(pacc2[p]),
                                      __int_as_float(pacc2[16 + p]),
                                      __int_as_float(pacc2[32 + p]),
                                      __int_as_float(pacc2[48 + p]));

        const int b0q = ((((1 - a) * 2 + (1 - bb)) * 2) + 1) * 16;  // c=0 -> kc=1
        const int b1q = ((((1 - a) * 2 + (1 - bb)) * 2) + 0) * 16;  // c=1 -> kc=0
        float4 t0q[4], t1q[4];
        #pragma unroll
        for (int q = 0; q < 4; ++q) {
            float4 a0 = wt1[b0q + q],      a1 = wt1[b0q + 4 + q];
            float4 a2 = wt1[b0q + 8 + q],  a3 = wt1[b0q + 12 + q];
            float4 c0 = wt1[b1q + q],      c1 = wt1[b1q + 4 + q];
            float4 c2 = wt1[b1q + 8 + q],  c3 = wt1[b1q + 12 + q];
            float4 s0, s1;
            s0.x = hv.x * a0.x + hv.y * a1.x + hv.z * a2.x + hv.w * a3.x;
            s0.y = hv.x * a0.y + hv.y * a1.y + hv.z * a2.y + hv.w * a3.y;
            s0.z = hv.x * a0.z + hv.y * a1.z + hv.z * a2.z + hv.w * a3.z;
            s0.w = hv.x * a0.w + hv.y * a1.w + hv.z * a2.w + hv.w * a3.w;
            s1.x = hv.x * c0.x + hv.y * c1.x + hv.z * c2.x + hv.w * c3.x;
            s1.y = hv.x * c0.y + hv.y * c1.y + hv.z * c2.y + hv.w * c3.y;
            s1.z = hv.x * c0.z + hv.y * c1.z + hv.z * c2.z + hv.w * c3.z;
            s1.w = hv.x * c0.w + hv.y * c1.w + hv.z * c2.w + hv.w * c3.w;
            t0q[q] = make_float4(fmaxf(s0.x, 0.f), fmaxf(s0.y, 0.f),
                                 fmaxf(s0.z, 0.f), fmaxf(s0.w, 0.f));
            t1q[q] = make_float4(fmaxf(s1.x, 0.f), fmaxf(s1.y, 0.f),
                                 fmaxf(s1.z, 0.f), fmaxf(s1.w, 0.f));
        }

        const int d  = 4 * bz2 + 2 * a + e;
        const int hh = 4 * py + 2 * bb + f;
        const int be = ((1 - e) * 2 + (1 - f)) * 2;
        const float4* wg0 = &wt2[(be + 1) * 4];   // g=0 -> kg=1
        const float4* wg1 = &wt2[(be + 0) * 4];   // g=1 -> kg=0
        float s00 = dot4(t0q[0], wg0[0]) + dot4(t0q[1], wg0[1])
                  + dot4(t0q[2], wg0[2]) + dot4(t0q[3], wg0[3]);
        float s01 = dot4(t0q[0], wg1[0]) + dot4(t0q[1], wg1[1])
                  + dot4(t0q[2], wg1[2]) + dot4(t0q[3], wg1[3]);
        float s10 = dot4(t1q[0], wg0[0]) + dot4(t1q[1], wg0[1])
                  + dot4(t1q[2], wg0[2]) + dot4(t1q[3], wg0[3]);
        float s11 = dot4(t1q[0], wg1[0]) + dot4(t1q[1], wg1[1])
                  + dot4(t1q[2], wg1[2]) + dot4(t1q[3], wg1[3]);
        float4 o;
        o.x = mm / (1.f + __expf(-s00));
        o.y = mm / (1.f + __expf(-s01));
        o.z = mm / (1.f + __expf(-s10));
        o.w = mm / (1.f + __expf(-s11));
        *(float4*)&out[((b * G + d) * G + hh) * G + 4 * pxq] = o;
    }
}

extern "C" void kernel_launch(void* const* d_in, const int* in_sizes, int n_in,
                              void* d_out, int out_size, void* d_ws, size_t ws_size,
                              hipStream_t stream) {
    (void)in_sizes; (void)n_in; (void)out_size; (void)d_ws; (void)ws_size;
    const float* x   = (const float*)d_in[0];
    const float* W1  = (const float*)d_in[1];
    const float* W2  = (const float*)d_in[2];
    const float* Wt1 = (const float*)d_in[3];
    const float* Wt2 = (const float*)d_in[4];
    const int*   occ = (const int*)d_in[5];
    float* out = (float*)d_out;

    k_fused<<<dim3(8, 8, 64), dim3(256), 0, stream>>>(x, occ, W1, W2, Wt1, Wt2, out);
}

// Round 8
// 172.355 us; speedup vs baseline: 1.4408x; 1.2952x over previous
//
#include <hip/hip_runtime.h>
#include <hip/hip_fp16.h>

#define G 128

typedef _Float16 h2_t __attribute__((ext_vector_type(2)));

union U16 { uint4 u; h2_t h2[4]; };
union HV  { uint4 u; h2_t h2[4]; };
union PK2 { uint2 u; h2_t h[2]; };

__device__ __forceinline__ float dot2f(h2_t a, h2_t b, float c) {
#if __has_builtin(__builtin_amdgcn_fdot2)
    return __builtin_amdgcn_fdot2(a, b, c, false);
#else
    return c + (float)a.x * (float)b.x + (float)a.y * (float)b.y;
#endif
}

__device__ __forceinline__ float dot4(float4 a, float4 b) {
    return a.x * b.x + a.y * b.y + a.z * b.z + a.w * b.w;
}

// ---------------------------------------------------------------------------
// Kernel A: conv1 (3x3x3, 1->16, SAME) + relu + m0 + 2x2x2 maxpool.
// ROUND-8: back to the 2-kernel structure (fusion = 3x halo recompute +
// 5-barrier serial chain at 3 blk/CU; 154us, abandoned). This version
// combines, for the first time, BOTH proven levers with SMALL LDS:
//  * region 16x16x4 (was 16x16x8): LDS 16.5KB -> 8 blk/CU (wave-capped),
//    grid 4096 -> 16 blocks/CU queued (latency-bound => residency is king).
//  * interleaved staging (VGPR-light; reg-staging measured neutral in R3 and
//    spills under bounds, R2); active-child list built in the staging pass;
//    compacted compute (~102 children/block at 10%); atomicMax f32-bit pool
//    (relu>=0 => int-monotonic; fp16<->f32 lossless). All verified pieces.
// ---------------------------------------------------------------------------
__global__ __launch_bounds__(256)
void k_conv1_pool(const float* __restrict__ x, const int* __restrict__ occ,
                  const float* __restrict__ W1,
                  __half* __restrict__ h1p, float* __restrict__ m1)
{
    // sx: (lz,ly,lx) at (lz*18+ly)*24+lx, lz in [0,6), ly in [0,18), lx in [0,24)
    __shared__ __align__(16) _Float16       sx[6 * 18 * 24];   // 5184 B
    __shared__ __align__(16) int            pacc[16 * 128];    // 8192 B
    __shared__ __align__(4)  unsigned short slist[1024];       // 2048 B
    __shared__ __align__(16) h2_t           w1L[216];          // 864 B
    __shared__ __align__(4)  unsigned char  sm1[128];
    __shared__ int                          scnt;

    const int bx = blockIdx.x, by = blockIdx.y;
    const int b  = blockIdx.z >> 5, bz4 = blockIdx.z & 31;     // 32 z-slabs of 4
    const int tid = threadIdx.x;

    const int z0 = bz4 * 4 - 1, y0 = by * 16 - 1;
    const int base_b = b * G * G * G;

    if (tid == 0) scnt = 0;
    {
        uint4 z4 = make_uint4(0u, 0u, 0u, 0u);
        ((uint4*)pacc)[tid]       = z4;
        ((uint4*)pacc)[tid + 256] = z4;
    }
    if (tid < 32) ((unsigned*)sm1)[tid] = 0u;
    if (tid < 216) {
        float2 f = ((const float2*)W1)[tid];   // w1L[i] = (W1[2i], W1[2i+1])
        h2_t w; w.x = (_Float16)f.x; w.y = (_Float16)f.y;
        w1L[tid] = w;
    }
    __syncthreads();   // zeros/counter visible before list atomics

    // ---- staging + active-child list, interleaved (648 aligned chunks) ----
    #pragma unroll
    for (int it = 0; it < 3; ++it) {
        int c = it * 256 + tid;
        if (c < 648) {
            int row = c / 6, seg = c - row * 6;    // row in [0,108)
            int lz = row / 18, ly = row - lz * 18;
            int gz = z0 + lz, gy = y0 + ly, gxc = (bx << 4) - 4 + (seg << 2);
            bool inb = (unsigned)gz < 128u && (unsigned)gy < 128u && (unsigned)gxc < 128u;
            int gi = inb ? base_b + (gz * G + gy) * G + gxc : base_b;
            int4   o4 = *(const int4*)(occ + gi);
            float4 x4 = *(const float4*)(x + gi);
            if (!inb) o4 = make_int4(1, 1, 1, 1);
            h2_t p01, p23;
            p01.x = (o4.x == 0) ? (_Float16)x4.x : (_Float16)0.f;
            p01.y = (o4.y == 0) ? (_Float16)x4.y : (_Float16)0.f;
            p23.x = (o4.z == 0) ? (_Float16)x4.z : (_Float16)0.f;
            p23.y = (o4.w == 0) ? (_Float16)x4.w : (_Float16)0.f;
            PK2 pk; pk.h[0] = p01; pk.h[1] = p23;
            *(uint2*)&sx[row * 24 + (seg << 2)] = pk.u;

            // children: lz in [1,4], ly in [1,16], lx in [4,19]
            if ((unsigned)(lz - 1) < 4u && (unsigned)(ly - 1) < 16u) {
                const int lx0 = seg << 2;
                int mb = 0;
                if (o4.x == 0 && (unsigned)(lx0 + 0 - 4) < 16u) mb |= 1;
                if (o4.y == 0 && (unsigned)(lx0 + 1 - 4) < 16u) mb |= 2;
                if (o4.z == 0 && (unsigned)(lx0 + 2 - 4) < 16u) mb |= 4;
                if (o4.w == 0 && (unsigned)(lx0 + 3 - 4) < 16u) mb |= 8;
                if (mb) {
                    int base = atomicAdd(&scnt, __popc(mb));
                    const int tb = ((lz - 1) >> 1) * 64 + ((ly - 1) >> 1) * 8;
                    #pragma unroll
                    for (int j = 0; j < 4; ++j) {
                        if (mb & (1 << j)) {
                            const int lxv = lx0 + j;
                            slist[base++] = (unsigned short)((lz << 10) | (ly << 5) | lxv);
                            sm1[tb + ((lxv - 4) >> 1)] = (unsigned char)1;  // benign race
                        }
                    }
                }
            }
        }
    }
    __syncthreads();

    const int n = scnt;   // ~102 of 1024 at 10% density

    // ---- compacted conv1 + pool (atomicMax on relu'd f32 bits) ----
    {
        const h2_t zero = (h2_t)(_Float16)0.f;
        for (int kb = 0; kb < n; kb += 256) {
            const int idx = kb + tid;
            if (idx < n) {
                const int e  = slist[idx];
                const int lx = e & 31, ly = (e >> 5) & 31, lz = e >> 10;
                const int sb = (lz * 18 + ly) * 24 + lx;
                h2_t acc[8];
                #pragma unroll
                for (int c = 0; c < 8; ++c) acc[c] = zero;
                #pragma unroll
                for (int kz = 0; kz < 3; ++kz)
                #pragma unroll
                for (int ky = 0; ky < 3; ++ky)
                #pragma unroll
                for (int kx = 0; kx < 3; ++kx) {
                    _Float16 v = sx[sb + (kz - 1) * 432 + (ky - 1) * 24 + (kx - 1)];
                    h2_t v2 = {v, v};
                    const h2_t* w = &w1L[((kz * 3 + ky) * 3 + kx) * 8];  // uniform
                    #pragma unroll
                    for (int c = 0; c < 8; ++c) acc[c] = v2 * w[c] + acc[c];
                }
                const int cell = ((lz - 1) >> 1) * 64 + ((ly - 1) >> 1) * 8 + ((lx - 4) >> 1);
                #pragma unroll
                for (int c = 0; c < 8; ++c) {
                    atomicMax(&pacc[(2 * c) * 128 + cell],
                              __float_as_int(fmaxf((float)acc[c].x, 0.f)));
                    atomicMax(&pacc[(2 * c + 1) * 128 + cell],
                              __float_as_int(fmaxf((float)acc[c].y, 0.f)));
                }
            }
        }
    }
    __syncthreads();

    // ---- epilogue: 128 pooled cells -> h1p (fp16 x16) + m1 ----
    if (tid < 128) {
        const int tx = tid & 7, ty = (tid >> 3) & 7, tz = tid >> 6;
        const int pz = bz4 * 2 + tz, py = by * 8 + ty, px = bx * 8 + tx;
        const int vidx = ((b * 64 + pz) * 64 + py) * 64 + px;
        HV p0, p1;
        #pragma unroll
        for (int c = 0; c < 4; ++c) {
            h2_t a, bq;
            a.x  = (_Float16)__int_as_float(pacc[(2 * c) * 128 + tid]);
            a.y  = (_Float16)__int_as_float(pacc[(2 * c + 1) * 128 + tid]);
            bq.x = (_Float16)__int_as_float(pacc[(8 + 2 * c) * 128 + tid]);
            bq.y = (_Float16)__int_as_float(pacc[(9 + 2 * c) * 128 + tid]);
            p0.h2[c] = a; p1.h2[c] = bq;
        }
        uint4* o = (uint4*)&h1p[(size_t)vidx * 16];
        o[0] = p0.u;
        o[1] = p1.u;
        m1[vidx] = sm1[tid] ? 1.f : 0.f;
    }
}

// ---------------------------------------------------------------------------
// Kernel B: conv2 (3x3x3, 16->4) + relu + m1 + pool + FULL DECODER.
// R4's verified kernel (went 64 -> <44us) with the region halved again:
// 8x8x2 level-1 outputs, tile [2][4x10x10] = 12.8KB, total LDS ~19.5KB ->
// 8 blk/CU (wave-capped), grid 4096 = 16/CU queued. m1 compaction (~57%),
// atomicMax pool, decoder = 16 parents x (a,bb,e,f) = 256 thr, 1 store each.
// ---------------------------------------------------------------------------
__global__ __launch_bounds__(256)
void k_conv2_dec(const __half* __restrict__ h1p, const float* __restrict__ m1,
                 const float* __restrict__ W2,
                 const float* __restrict__ Wt1, const float* __restrict__ Wt2,
                 float* __restrict__ out)
{
    __shared__ __align__(16) uint4 tile[800];   // [half][4*10*10] = 12.8 KB
    __shared__ float4              wt1[128];    // 2048 B
    __shared__ float4              wt2[32];     // 512 B
    __shared__ __align__(16) h2_t  w2L[864];    // 3456 B
    __shared__ int                 pacc2[64];   // [co][parent]
    __shared__ int                 pm[16];
    __shared__ unsigned char       clist[128];
    __shared__ int                 scnt;

    const int bx = blockIdx.x, by = blockIdx.y;
    const int b  = blockIdx.z >> 5, bzq = blockIdx.z & 31;   // 32 z-slabs of 2
    const int tid = threadIdx.x;

    const int z0 = bzq * 2 - 1, y0 = by * 8 - 1, x0 = bx * 8 - 1;

    // ---- reg-stage the 400-voxel tile (2x uint4 x 2 iters in flight) ----
    uint4 ra[2], rb4[2];
    #pragma unroll
    for (int it = 0; it < 2; ++it) {
        int g = it * 256 + tid;
        int gg = g < 400 ? g : 399;
        int z = gg / 100, r = gg - z * 100, y = r / 10, xx = r - y * 10;
        int gz = z0 + z, gy = y0 + y, gx = x0 + xx;
        bool inb = (unsigned)gz < 64u && (unsigned)gy < 64u && (unsigned)gx < 64u;
        size_t vi = inb ? (size_t)(((b * 64 + gz) * 64 + gy) * 64 + gx) : 0;
        const uint4* src = (const uint4*)&h1p[vi * 16];
        ra[it]  = src[0];
        rb4[it] = src[1];
    }

    // own output voxel's m1 (tid < 128 only)
    const int ox_ = tid & 7, oy_ = (tid >> 3) & 7, oz_ = tid >> 6;
    float mv = 0.f;
    if (tid < 128)
        mv = m1[((b * 64 + (bzq * 2 + oz_)) * 64 + (by * 8 + oy_)) * 64
                + (bx * 8 + ox_)];

    // ---- weights + small-state init (hides under loads above) ----
    if (tid == 0) scnt = 0;
    if (tid < 128) wt1[tid] = ((const float4*)Wt1)[tid];
    if (tid < 32)  wt2[tid] = ((const float4*)Wt2)[tid];
    if (tid < 64)  pacc2[tid] = 0;
    if (tid < 16)  pm[tid] = 0;
    #pragma unroll
    for (int it = 0; it < 4; ++it) {
        int i = it * 256 + tid;
        if (i < 864) {
            int t = i >> 5, rr = i & 31, co = rr >> 3, p = rr & 7;
            h2_t w;
            w.x = (_Float16)W2[t * 64 + (2 * p) * 4 + co];
            w.y = (_Float16)W2[t * 64 + (2 * p + 1) * 4 + co];
            w2L[i] = w;
        }
    }
    __syncthreads();   // init visible before list atomics / pm stores

    // ---- tile write + active-list build ----
    #pragma unroll
    for (int it = 0; it < 2; ++it) {
        int g = it * 256 + tid;
        if (g < 400) {
            int z = g / 100, r = g - z * 100, y = r / 10, xx = r - y * 10;
            int gz = z0 + z, gy = y0 + y, gx = x0 + xx;
            bool inb = (unsigned)gz < 64u && (unsigned)gy < 64u && (unsigned)gx < 64u;
            uint4 a0 = ra[it], a1 = rb4[it];
            if (!inb) { a0 = make_uint4(0u, 0u, 0u, 0u); a1 = a0; }
            tile[g]       = a0;
            tile[400 + g] = a1;
        }
    }
    {
        const int lane = tid & 63;
        bool act = (tid < 128) && (mv != 0.f);
        unsigned long long bal = __ballot(act);
        int wtot = __popcll(bal);
        int wbase = 0;
        if (lane == 0 && wtot) wbase = atomicAdd(&scnt, wtot);
        wbase = __shfl(wbase, 0);
        if (act) {
            int pre = __popcll(bal & ((1ull << lane) - 1ull));
            clist[wbase + pre] = (unsigned char)tid;
            pm[(oy_ >> 1) * 4 + (ox_ >> 1)] = 1;   // benign race
        }
    }
    __syncthreads();

    const int n = scnt;   // <=128, ~73 at 57% level-1 density

    // ---- conv2 + relu + pool on ACTIVE outputs only ----
    if (tid < n) {
        const int code = clist[tid];
        const int ox = code & 7, oy = (code >> 3) & 7, oz = code >> 6;
        float acc[4] = {0.f, 0.f, 0.f, 0.f};
        #pragma unroll
        for (int kz = 0; kz < 3; ++kz)
        #pragma unroll
        for (int ky = 0; ky < 3; ++ky) {
            const int rb = ((oz + kz) * 10 + (oy + ky)) * 10 + ox;
            h2_t hp[2][3][4];
            #pragma unroll
            for (int hh = 0; hh < 2; ++hh)
            #pragma unroll
            for (int xi = 0; xi < 3; ++xi) {
                U16 a; a.u = tile[hh * 400 + rb + xi];
                #pragma unroll
                for (int p = 0; p < 4; ++p) hp[hh][xi][p] = a.h2[p];
            }
            const int t3 = (kz * 3 + ky) * 3;
            #pragma unroll
            for (int kx = 0; kx < 3; ++kx) {
                const h2_t* w = &w2L[(t3 + kx) * 32];   // uniform -> broadcast
                #pragma unroll
                for (int co = 0; co < 4; ++co) {
                    float a = acc[co];
                    #pragma unroll
                    for (int hh = 0; hh < 2; ++hh)
                    #pragma unroll
                    for (int p = 0; p < 4; ++p)
                        a = dot2f(hp[hh][kx][p], w[co * 8 + 4 * hh + p], a);
                    acc[co] = a;
                }
            }
        }
        const int parent = (oy >> 1) * 4 + (ox >> 1);
        #pragma unroll
        for (int co = 0; co < 4; ++co)
            atomicMax(&pacc2[co * 16 + parent],
                      __float_as_int(fmaxf(acc[co], 0.f)));
    }
    __syncthreads();

    // ---- decoder: thread = (parent p, a, bb, e, f) ----
    {
        const int p  = tid >> 4;
        const int a  = (tid >> 3) & 1;
        const int bb = (tid >> 2) & 1;
        const int e  = (tid >> 1) & 1;
        const int f  = tid & 1;
        const int pY = p >> 2, pq = p & 3;
        const int py = by * 4 + pY, pxq = bx * 4 + pq;

        const float mm = pm[p] ? 1.f : 0.f;
        const float4 hv = make_float4(__int_as_float(pacc2[p]),
                                      __int_as_float(pacc2[16 + p]),
                                      __int_as_float(pacc2[32 + p]),
                                      __int_as_float(pacc2[48 + p]));

        const int b0q = ((((1 - a) * 2 + (1 - bb)) * 2) + 1) * 16;  // c=0 -> kc=1
        const int b1q = ((((1 - a) * 2 + (1 - bb)) * 2) + 0) * 16;  // c=1 -> kc=0
        float4 t0q[4], t1q[4];
        #pragma unroll
        for (int q = 0; q < 4; ++q) {
            float4 a0 = wt1[b0q + q],      a1 = wt1[b0q + 4 + q];
            float4 a2 = wt1[b0q + 8 + q],  a3 = wt1[b0q + 12 + q];
            float4 c0 = wt1[b1q + q],      c1 = wt1[b1q + 4 + q];
            float4 c2 = wt1[b1q + 8 + q],  c3 = wt1[b1q + 12 + q];
            float4 s0, s1;
            s0.x = hv.x * a0.x + hv.y * a1.x + hv.z * a2.x + hv.w * a3.x;
            s0.y = hv.x * a0.y + hv.y * a1.y + hv.z * a2.y + hv.w * a3.y;
            s0.z = hv.x * a0.z + hv.y * a1.z + hv.z * a2.z + hv.w * a3.z;
            s0.w = hv.x * a0.w + hv.y * a1.w + hv.z * a2.w + hv.w * a3.w;
            s1.x = hv.x * c0.x + hv.y * c1.x + hv.z * c2.x + hv.w * c3.x;
            s1.y = hv.x * c0.y + hv.y * c1.y + hv.z * c2.y + hv.w * c3.y;
            s1.z = hv.x * c0.z + hv.y * c1.z + hv.z * c2.z + hv.w * c3.z;
            s1.w = hv.x * c0.w + hv.y * c1.w + hv.z * c2.w + hv.w * c3.w;
            t0q[q] = make_float4(fmaxf(s0.x, 0.f), fmaxf(s0.y, 0.f),
                                 fmaxf(s0.z, 0.f), fmaxf(s0.w, 0.f));
            t1q[q] = make_float4(fmaxf(s1.x, 0.f), fmaxf(s1.y, 0.f),
                                 fmaxf(s1.z, 0.f), fmaxf(s1.w, 0.f));
        }

        const int d  = 4 * bzq + 2 * a + e;
        const int hh = 4 * py + 2 * bb + f;
        const int be = ((1 - e) * 2 + (1 - f)) * 2;
        const float4* wg0 = &wt2[(be + 1) * 4];   // g=0 -> kg=1
        const float4* wg1 = &wt2[(be + 0) * 4];   // g=1 -> kg=0
        float s00 = dot4(t0q[0], wg0[0]) + dot4(t0q[1], wg0[1])
                  + dot4(t0q[2], wg0[2]) + dot4(t0q[3], wg0[3]);
        float s01 = dot4(t0q[0], wg1[0]) + dot4(t0q[1], wg1[1])
                  + dot4(t0q[2], wg1[2]) + dot4(t0q[3], wg1[3]);
        float s10 = dot4(t1q[0], wg0[0]) + dot4(t1q[1], wg0[1])
                  + dot4(t1q[2], wg0[2]) + dot4(t1q[3], wg0[3]);
        float s11 = dot4(t1q[0], wg1[0]) + dot4(t1q[1], wg1[1])
                  + dot4(t1q[2], wg1[2]) + dot4(t1q[3], wg1[3]);
        float4 o;
        o.x = mm / (1.f + __expf(-s00));
        o.y = mm / (1.f + __expf(-s01));
        o.z = mm / (1.f + __expf(-s10));
        o.w = mm / (1.f + __expf(-s11));
        *(float4*)&out[((b * G + d) * G + hh) * G + 4 * pxq] = o;
    }
}

extern "C" void kernel_launch(void* const* d_in, const int* in_sizes, int n_in,
                              void* d_out, int out_size, void* d_ws, size_t ws_size,
                              hipStream_t stream) {
    (void)in_sizes; (void)n_in; (void)out_size; (void)ws_size;
    const float* x   = (const float*)d_in[0];
    const float* W1  = (const float*)d_in[1];
    const float* W2  = (const float*)d_in[2];
    const float* Wt1 = (const float*)d_in[3];
    const float* Wt2 = (const float*)d_in[4];
    const int*   occ = (const int*)d_in[5];
    float* out = (float*)d_out;

    char* ws = (char*)d_ws;
    __half* h1p = (__half*)ws;                                  // 16 MB
    float*  m1  = (float*)(ws + 8388608ull * sizeof(__half));   // 2 MB

    k_conv1_pool<<<dim3(8, 8, 64), dim3(256), 0, stream>>>(x, occ, W1, h1p, m1);
    k_conv2_dec<<<dim3(8, 8, 64), dim3(256), 0, stream>>>(h1p, m1, W2, Wt1, Wt2, out);
}

// Round 9
// 147.204 us; speedup vs baseline: 1.6869x; 1.1709x over previous
//
#include <hip/hip_runtime.h>
#include <hip/hip_fp16.h>

#define G 128

typedef _Float16 h2_t __attribute__((ext_vector_type(2)));

union U16 { uint4 u; h2_t h2[4]; };
union HV  { uint4 u; h2_t h2[4]; };
union PK2 { uint2 u; h2_t h[2]; };

__device__ __forceinline__ float dot2f(h2_t a, h2_t b, float c) {
#if __has_builtin(__builtin_amdgcn_fdot2)
    return __builtin_amdgcn_fdot2(a, b, c, false);
#else
    return c + (float)a.x * (float)b.x + (float)a.y * (float)b.y;
#endif
}

__device__ __forceinline__ float dot4(float4 a, float4 b) {
    return a.x * b.x + a.y * b.y + a.z * b.z + a.w * b.w;
}

// ---------------------------------------------------------------------------
// Kernel A: conv1 (3x3x3, 1->16, SAME) + relu + m0 + 2x2x2 maxpool.
// R3-EXACT (proven 12-15us by exact budget fit: R3 total = 70 + 12 + 64.2).
//  * reg-staged loads: all 10 16B loads in flight before any LDS write
//    (R8 dropped this -> conv1 regressed to ~46us; ledger: 34->15 came FROM
//    reg-staging with VGPR room).
//  * (256,1): (256,4) caps VGPR at 64 and spills the staging arrays (R2:
//    247MB scratch traffic). Reg staging + tight bounds are exclusive.
//  * compacted compute + atomicMax f32-bit pool (relu>=0 => monotonic).
// ADDED: block (0,0,0) also packs W2 -> w2h (global ws), replacing the k_prep
// dispatch (kernel-order guarantees visibility before kernel B).
// ---------------------------------------------------------------------------
__global__ __launch_bounds__(256, 1)
void k_conv1_pool(const float* __restrict__ x, const int* __restrict__ occ,
                  const float* __restrict__ W1, const float* __restrict__ W2,
                  __half* __restrict__ h1p, float* __restrict__ m1,
                  __half* __restrict__ w2h)
{
    // sx: (lz,ly,lx) at (lz*18+ly)*24 + lx, lx in [0,24); gx = bx*16 - 4 + lx
    __shared__ __align__(16) _Float16      sx[10 * 18 * 24];   // 8640 B
    __shared__ __align__(16) int           pacc[16 * 256];     // 16 KB [ch][cell]
    __shared__ __align__(4)  unsigned short slist[2048];       // 4 KB
    __shared__ __align__(16) h2_t          w1L[216];           // 864 B
    __shared__ __align__(4)  unsigned char sm1[256];
    __shared__ int                         scnt;

    const int bx = blockIdx.x, by = blockIdx.y;
    const int b  = blockIdx.z >> 4, zt = blockIdx.z & 15;
    const int tid = threadIdx.x;

    const int z0 = zt * 8 - 1, y0 = by * 16 - 1;
    const int base_b = b * G * G * G;

    // ---- issue ALL staging loads first (nothing dependent between them) ----
    int4   ro[5];
    float4 rx[5];
    #pragma unroll
    for (int it = 0; it < 5; ++it) {
        int c = it * 256 + tid;
        int cc = c < 1080 ? c : 1079;          // clamp: harmless duplicate load
        int row = cc / 6, seg = cc - row * 6;  // row in [0,180)
        int lz  = row / 18, ly = row - lz * 18;
        int gz = z0 + lz, gy = y0 + ly;
        int gxc = (bx << 4) - 4 + (seg << 2);
        bool inb = (unsigned)gz < 128u && (unsigned)gy < 128u && (unsigned)gxc < 128u;
        int gi = inb ? base_b + (gz * G + gy) * G + gxc : base_b;  // safe addr
        ro[it] = *(const int4*)(occ + gi);
        rx[it] = *(const float4*)(x + gi);
    }

    // ---- folded k_prep: block (0,0,0) packs W2 -> w2h for kernel B ----
    if (bx == 0 && by == 0 && blockIdx.z == 0) {
        #pragma unroll
        for (int it = 0; it < 4; ++it) {
            int i = it * 256 + tid;
            if (i < 864) {
                int t = i >> 5, rr = i & 31, co = rr >> 3, p = rr & 7;
                w2h[2 * i]     = __float2half(W2[t * 64 + (2 * p) * 4 + co]);
                w2h[2 * i + 1] = __float2half(W2[t * 64 + (2 * p + 1) * 4 + co]);
            }
        }
    }

    // ---- phase 0 LDS init (independent of the loads above) ----
    if (tid == 0) scnt = 0;
    {
        uint4 z4 = make_uint4(0u, 0u, 0u, 0u);
        uint4* p4 = (uint4*)pacc;
        p4[tid] = z4; p4[tid + 256] = z4; p4[tid + 512] = z4; p4[tid + 768] = z4;
    }
    if (tid < 64) ((unsigned*)sm1)[tid] = 0u;
    if (tid < 216) {
        float2 f = ((const float2*)W1)[tid];   // w1L[i] = (W1[2i], W1[2i+1])
        h2_t w; w.x = (_Float16)f.x; w.y = (_Float16)f.y;
        w1L[tid] = w;
    }
    __syncthreads();   // zero/init visible before list atomics & sm1 writes

    // ---- write loop: convert + LDS store + build active list in one pass ----
    #pragma unroll
    for (int it = 0; it < 5; ++it) {
        int c = it * 256 + tid;
        if (c < 1080) {
            int row = c / 6, seg = c - row * 6;
            int lz  = row / 18, ly = row - lz * 18;
            int gz = z0 + lz, gy = y0 + ly;
            int gxc = (bx << 4) - 4 + (seg << 2);
            bool inb = (unsigned)gz < 128u && (unsigned)gy < 128u && (unsigned)gxc < 128u;
            int4   o4 = ro[it];
            float4 x4 = rx[it];
            if (!inb) o4 = make_int4(1, 1, 1, 1);
            h2_t p01, p23;
            p01.x = (o4.x == 0) ? (_Float16)x4.x : (_Float16)0.f;
            p01.y = (o4.y == 0) ? (_Float16)x4.y : (_Float16)0.f;
            p23.x = (o4.z == 0) ? (_Float16)x4.z : (_Float16)0.f;
            p23.y = (o4.w == 0) ? (_Float16)x4.w : (_Float16)0.f;
            PK2 pk; pk.h[0] = p01; pk.h[1] = p23;
            *(uint2*)&sx[row * 24 + (seg << 2)] = pk.u;

            // interior chunks (lz 1..8, ly 1..16, seg 1..4) feed the list;
            // they are always fully in-bounds so o4 is real data.
            if ((unsigned)(lz - 1) < 8u && (unsigned)(ly - 1) < 16u &&
                (unsigned)(seg - 1) < 4u) {
                int mb = (o4.x == 0 ? 1 : 0) | (o4.y == 0 ? 2 : 0) |
                         (o4.z == 0 ? 4 : 0) | (o4.w == 0 ? 8 : 0);
                if (mb) {
                    int cnt  = __popc(mb);
                    int base = atomicAdd(&scnt, cnt);
                    int cz = lz - 1, cy = ly - 1, cx0v = (seg << 2) - 4;
                    int cellb = (cz >> 1) * 64 + (cy >> 1) * 8;
                    #pragma unroll
                    for (int j = 0; j < 4; ++j) {
                        if (mb & (1 << j)) {
                            slist[base++] = (unsigned short)((cz << 8) | (cy << 4) | (cx0v + j));
                            sm1[cellb + ((cx0v + j) >> 1)] = (unsigned char)1;  // benign race: all write 1
                        }
                    }
                }
            }
        }
    }
    __syncthreads();

    const int n = scnt;   // ~205 of 2048 at 10% density

    // ---- compute: one ACTIVE center per thread ----
    const h2_t zero = (h2_t)(_Float16)0.f;
    for (int kb = 0; kb < n; kb += 256) {
        const int idx = kb + tid;
        if (idx < n) {
            const int code = slist[idx];
            const int cz = code >> 8, cy = (code >> 4) & 15, cx = code & 15;
            const int sb = ((cz + 1) * 18 + (cy + 1)) * 24 + cx + 4;
            h2_t acc[8];
            #pragma unroll
            for (int c = 0; c < 8; ++c) acc[c] = zero;
            #pragma unroll
            for (int kz = 0; kz < 3; ++kz)
            #pragma unroll
            for (int ky = 0; ky < 3; ++ky)
            #pragma unroll
            for (int kx = 0; kx < 3; ++kx) {
                _Float16 v = sx[sb + (kz - 1) * 432 + (ky - 1) * 24 + (kx - 1)];
                h2_t v2 = {v, v};
                const h2_t* w = &w1L[((kz * 3 + ky) * 3 + kx) * 8];  // uniform -> broadcast
                #pragma unroll
                for (int c = 0; c < 8; ++c) acc[c] = v2 * w[c] + acc[c];
            }
            const int cell = (cz >> 1) * 64 + (cy >> 1) * 8 + (cx >> 1);
            #pragma unroll
            for (int c = 0; c < 8; ++c) {
                atomicMax(&pacc[(2 * c) * 256 + cell],
                          __float_as_int(fmaxf((float)acc[c].x, 0.f)));
                atomicMax(&pacc[(2 * c + 1) * 256 + cell],
                          __float_as_int(fmaxf((float)acc[c].y, 0.f)));
            }
        }
    }
    __syncthreads();

    // ---- epilogue: pooled cell tid -> h1p (fp16 x16) + m1 ----
    const int tx = tid & 7, ty = (tid >> 3) & 7, tz = tid >> 6;
    const int pz = zt * 4 + tz, py = by * 8 + ty, px = bx * 8 + tx;
    const int vidx = ((b * 64 + pz) * 64 + py) * 64 + px;
    HV p0, p1;
    #pragma unroll
    for (int c = 0; c < 4; ++c) {
        h2_t a, bq;
        a.x  = (_Float16)__int_as_float(pacc[(2 * c) * 256 + tid]);
        a.y  = (_Float16)__int_as_float(pacc[(2 * c + 1) * 256 + tid]);
        bq.x = (_Float16)__int_as_float(pacc[(8 + 2 * c) * 256 + tid]);
        bq.y = (_Float16)__int_as_float(pacc[(9 + 2 * c) * 256 + tid]);
        p0.h2[c] = a; p1.h2[c] = bq;
    }
    uint4* o = (uint4*)&h1p[(size_t)vidx * 16];
    o[0] = p0.u;
    o[1] = p1.u;
    m1[vidx] = sm1[tid] ? 1.f : 0.f;
}

// ---------------------------------------------------------------------------
// Kernel B: conv2 (3x3x3, 16->4) + relu + m1 + pool + FULL DECODER.
// ROUND-0-EXACT (the component of the best-ever total 144: exact fit
// 70 + 34 + 40). 8x8x8 region (1024 blocks: per-block fixed cost amortized
// 4x better than R8's 4096 — R8's VALU was ~75% overhead), two-pass channel
// halves (tile 17.6KB, ~24KB total -> 6 blk/CU), weights from global w2h via
// uniform scalar loads (NO per-block conversion), dense j-pair compute.
// ---------------------------------------------------------------------------
__global__ __launch_bounds__(256)
void k_conv2_dec(const __half* __restrict__ h1p, const float* __restrict__ m1,
                 const h2_t* __restrict__ w2h,
                 const float* __restrict__ Wt1, const float* __restrict__ Wt2,
                 float* __restrict__ out)
{
    __shared__ uint4  tile[1100];   // 10*10*11 voxels, 8ch fp16 = 17.6 KB
    __shared__ float4 wt1[128];     // Wt1: 512 floats
    __shared__ float4 wt2[32];      // Wt2: 128 floats
    __shared__ float4 sh_h[64];     // pooled h2 per parent
    __shared__ float  sh_m[64];     // pooled m2 per parent

    const int bx = blockIdx.x, by = blockIdx.y;
    const int b  = blockIdx.z >> 3, bz = blockIdx.z & 7;
    const int tid = threadIdx.x;

    if (tid < 128) wt1[tid] = ((const float4*)Wt1)[tid];
    if (tid < 32)  wt2[tid] = ((const float4*)Wt2)[tid];

    const int z0 = bz * 8 - 1, y0 = by * 8 - 1, x0 = bx * 8 - 1;

    const int dy = tid & 1, dz = (tid >> 1) & 1;
    const int qx = (tid >> 2) & 3, Y = (tid >> 4) & 3, Z = (tid >> 6) & 3;
    const int cx0 = 2 * qx, cy = 2 * Y + dy, cz = 2 * Z + dz;

    float acc[2][4] = {{0.f, 0.f, 0.f, 0.f}, {0.f, 0.f, 0.f, 0.f}};

    for (int h = 0; h < 2; ++h) {
        if (h) __syncthreads();
        #pragma unroll
        for (int it = 0; it < 5; ++it) {
            int g = it * 256 + tid;
            if (g < 1100) {
                int z = g / 110, r = g - z * 110, y = r / 11, xx = r - y * 11;
                int gz = z0 + z, gy = y0 + y, gx = x0 + xx;
                uint4 a = make_uint4(0u, 0u, 0u, 0u);
                if ((unsigned)gz < 64u && (unsigned)gy < 64u && (unsigned)gx < 64u)
                    a = ((const uint4*)&h1p[(size_t)(((b * 64 + gz) * 64 + gy) * 64 + gx) * 16])[h];
                tile[g] = a;
            }
        }
        __syncthreads();

        #pragma unroll
        for (int kz = 0; kz < 3; ++kz)
        #pragma unroll
        for (int ky = 0; ky < 3; ++ky) {
            const int rb = (cz + kz) * 110 + (cy + ky) * 11 + cx0;
            h2_t hp[4][4];
            #pragma unroll
            for (int xi = 0; xi < 4; ++xi) {
                U16 a; a.u = tile[rb + xi];
                #pragma unroll
                for (int p = 0; p < 4; ++p) hp[xi][p] = a.h2[p];
            }
            const int t3 = (kz * 3 + ky) * 3;
            #pragma unroll
            for (int kx = 0; kx < 3; ++kx) {
                const h2_t* w = w2h + (t3 + kx) * 32 + 4 * h;   // uniform -> s_load
                #pragma unroll
                for (int j = 0; j < 2; ++j) {
                    #pragma unroll
                    for (int co = 0; co < 4; ++co) {
                        float a = acc[j][co];
                        #pragma unroll
                        for (int p = 0; p < 4; ++p)
                            a = dot2f(hp[kx + j][p], w[co * 8 + p], a);
                        acc[j][co] = a;
                    }
                }
            }
        }
    }

    // ---- mask + relu + pool ----
    const int gcz = bz * 8 + cz, gcy = by * 8 + cy, gcx = bx * 8 + cx0;
    const float mv0 = m1[((b * 64 + gcz) * 64 + gcy) * 64 + gcx];
    const float mv1 = m1[((b * 64 + gcz) * 64 + gcy) * 64 + gcx + 1];
    float m = fmaxf(mv0, mv1);
    float r0 = fmaxf(fmaxf(acc[0][0], 0.f) * mv0, fmaxf(acc[1][0], 0.f) * mv1);
    float r1 = fmaxf(fmaxf(acc[0][1], 0.f) * mv0, fmaxf(acc[1][1], 0.f) * mv1);
    float r2 = fmaxf(fmaxf(acc[0][2], 0.f) * mv0, fmaxf(acc[1][2], 0.f) * mv1);
    float r3 = fmaxf(fmaxf(acc[0][3], 0.f) * mv0, fmaxf(acc[1][3], 0.f) * mv1);

    #pragma unroll
    for (int mask = 1; mask <= 2; mask <<= 1) {
        r0 = fmaxf(r0, __shfl_xor(r0, mask));
        r1 = fmaxf(r1, __shfl_xor(r1, mask));
        r2 = fmaxf(r2, __shfl_xor(r2, mask));
        r3 = fmaxf(r3, __shfl_xor(r3, mask));
        m  = fmaxf(m,  __shfl_xor(m,  mask));
    }
    if ((tid & 3) == 0) {
        int p = Z * 16 + Y * 4 + qx;
        sh_h[p] = make_float4(r0, r1, r2, r3);
        sh_m[p] = m;
    }
    __syncthreads();

    // ---- decoder phase: thread = (parent p, a, bb) ----
    {
        const int p  = tid >> 2;
        const int a  = (tid >> 1) & 1;
        const int bb = tid & 1;
        const int pZ = p >> 4, pY = (p >> 2) & 3, pq = p & 3;
        const int pz = bz * 4 + pZ, py = by * 4 + pY, pxq = bx * 4 + pq;

        const float mm = sh_m[p];
        const float4 hv = sh_h[p];

        const int b0q = ((((1 - a) * 2 + (1 - bb)) * 2) + 1) * 16;  // c=0 -> kc=1
        const int b1q = ((((1 - a) * 2 + (1 - bb)) * 2) + 0) * 16;  // c=1 -> kc=0
        float4 t0q[4], t1q[4];
        #pragma unroll
        for (int q = 0; q < 4; ++q) {
            float4 a0 = wt1[b0q + q],      a1 = wt1[b0q + 4 + q];
            float4 a2 = wt1[b0q + 8 + q],  a3 = wt1[b0q + 12 + q];
            float4 c0 = wt1[b1q + q],      c1 = wt1[b1q + 4 + q];
            float4 c2 = wt1[b1q + 8 + q],  c3 = wt1[b1q + 12 + q];
            float4 s0, s1;
            s0.x = hv.x * a0.x + hv.y * a1.x + hv.z * a2.x + hv.w * a3.x;
            s0.y = hv.x * a0.y + hv.y * a1.y + hv.z * a2.y + hv.w * a3.y;
            s0.z = hv.x * a0.z + hv.y * a1.z + hv.z * a2.z + hv.w * a3.z;
            s0.w = hv.x * a0.w + hv.y * a1.w + hv.z * a2.w + hv.w * a3.w;
            s1.x = hv.x * c0.x + hv.y * c1.x + hv.z * c2.x + hv.w * c3.x;
            s1.y = hv.x * c0.y + hv.y * c1.y + hv.z * c2.y + hv.w * c3.y;
            s1.z = hv.x * c0.z + hv.y * c1.z + hv.z * c2.z + hv.w * c3.z;
            s1.w = hv.x * c0.w + hv.y * c1.w + hv.z * c2.w + hv.w * c3.w;
            t0q[q] = make_float4(fmaxf(s0.x, 0.f), fmaxf(s0.y, 0.f),
                                 fmaxf(s0.z, 0.f), fmaxf(s0.w, 0.f));
            t1q[q] = make_float4(fmaxf(s1.x, 0.f), fmaxf(s1.y, 0.f),
                                 fmaxf(s1.z, 0.f), fmaxf(s1.w, 0.f));
        }

        #pragma unroll
        for (int e = 0; e < 2; ++e) {
            #pragma unroll
            for (int f = 0; f < 2; ++f) {
                const int d  = 4 * pz + 2 * a + e;
                const int hh = 4 * py + 2 * bb + f;
                const int be = ((1 - e) * 2 + (1 - f)) * 2;
                const float4* wg0 = &wt2[(be + 1) * 4];   // g=0 -> kg=1
                const float4* wg1 = &wt2[(be + 0) * 4];   // g=1 -> kg=0
                float s00 = dot4(t0q[0], wg0[0]) + dot4(t0q[1], wg0[1])
                          + dot4(t0q[2], wg0[2]) + dot4(t0q[3], wg0[3]);
                float s01 = dot4(t0q[0], wg1[0]) + dot4(t0q[1], wg1[1])
                          + dot4(t0q[2], wg1[2]) + dot4(t0q[3], wg1[3]);
                float s10 = dot4(t1q[0], wg0[0]) + dot4(t1q[1], wg0[1])
                          + dot4(t1q[2], wg0[2]) + dot4(t1q[3], wg0[3]);
                float s11 = dot4(t1q[0], wg1[0]) + dot4(t1q[1], wg1[1])
                          + dot4(t1q[2], wg1[2]) + dot4(t1q[3], wg1[3]);
                float4 o;
                o.x = mm / (1.f + __expf(-s00));
                o.y = mm / (1.f + __expf(-s01));
                o.z = mm / (1.f + __expf(-s10));
                o.w = mm / (1.f + __expf(-s11));
                *(float4*)&out[((b * G + d) * G + hh) * G + 4 * pxq] = o;
            }
        }
    }
}

extern "C" void kernel_launch(void* const* d_in, const int* in_sizes, int n_in,
                              void* d_out, int out_size, void* d_ws, size_t ws_size,
                              hipStream_t stream) {
    (void)in_sizes; (void)n_in; (void)out_size; (void)ws_size;
    const float* x   = (const float*)d_in[0];
    const float* W1  = (const float*)d_in[1];
    const float* W2  = (const float*)d_in[2];
    const float* Wt1 = (const float*)d_in[3];
    const float* Wt2 = (const float*)d_in[4];
    const int*   occ = (const int*)d_in[5];
    float* out = (float*)d_out;

    char* ws = (char*)d_ws;
    __half* h1p = (__half*)ws;                                  // 16 MB
    float*  m1  = (float*)(ws + 8388608ull * sizeof(__half));   // 2 MB
    __half* w2h = (__half*)(m1 + 524288);                       // 3456 B

    k_conv1_pool<<<dim3(8, 8, 32), dim3(256), 0, stream>>>(x, occ, W1, W2, h1p, m1, w2h);
    k_conv2_dec<<<dim3(8, 8, 16), dim3(256), 0, stream>>>(h1p, m1, (const h2_t*)w2h, Wt1, Wt2, out);
}